// Round 4
// baseline (4489.964 us; speedup 1.0000x reference)
//
#include <hip/hip_runtime.h>

// Greedy NMS: keep[i] = !any(keep[j] for j in knn[i] if j < i)
//
// Structure (validated round 3): stream-ordered multi-launch chain, no
// inter-block sync, no workspace. Chunk c's launch reads final flags of rows
// < c*1024 directly from d_out (kernel-boundary coherence), resolves
// intra-chunk deps with an LDS monotone fixed-point, writes its flags.
// A final elementwise kernel emits kept_knn.
//
// Output encoding (fingerprinted round 3): INT32.
//   d_out[0..M)        : kept flags, 1 / 0          (ref output 0: bool)
//   d_out[M..M+M*64)   : kept_knn, idx or 150000    (ref output 1: int64)
//
// d_in[0]: nodes (float, unused by the reference math)
// d_in[1]: node_knn_indices (int32, M*64, values in [0, 150000])

#define M_ROWS 150000
#define KNN    64
#define CH     1024
#define NCH    ((M_ROWS + CH - 1) / CH)   // 147
#define ICAP   8

__global__ __launch_bounds__(CH) void flag_chunk_kernel(
    const int* __restrict__ knn,
    int* __restrict__ out,
    int base)
{
  const int t     = threadIdx.x;
  const int row   = base + t;
  const bool valid = row < M_ROWS;

  // load this row's 64 predecessor indices into registers (static-indexed)
  int v[KNN];
  if (valid) {
    const int4* rp = (const int4*)(knn + (long long)row * KNN);
#pragma unroll
    for (int q = 0; q < KNN / 4; ++q) {
      int4 d = rp[q];
      v[4*q+0] = d.x; v[4*q+1] = d.y; v[4*q+2] = d.z; v[4*q+3] = d.w;
    }
  } else {
#pragma unroll
    for (int k = 0; k < KNN; ++k) v[k] = M_ROWS;   // sentinel: never a pred
  }

  // external suppression (rows < base: final flags already in d_out)
  // + intra-chunk predecessor list (base <= j < row)
  bool supp = false;
  int  ic = 0;
  unsigned short il[ICAP];
#pragma unroll
  for (int k = 0; k < KNN; ++k) {
    int j = v[k];
    if (valid && j < row) {              // strict: j==row never suppresses (ref semantics)
      if (j < base) {
        if (!supp && out[j] != 0) supp = true;
      } else {
        if (ic < ICAP) il[ic] = (unsigned short)(j - base);
        ++ic;
      }
    }
  }
  const bool ovf = ic > ICAP;            // fall back to register rescan (≈ never)
  if (ovf) ic = ICAP;

  __shared__ unsigned char st[CH];       // 0 unknown, 1 kept, 2 suppressed
  st[t] = (!valid || supp) ? (unsigned char)2
        : ((ic == 0 && !ovf) ? (unsigned char)1 : (unsigned char)0);
  __syncthreads();

  // monotone fixed-point: a row resolves once all its intra-chunk preds resolve
  for (int it = 0; it < CH; ++it) {
    if (st[t] == 0) {
      bool anyK = false, allD = true;
      if (!ovf) {
        for (int q = 0; q < ic; ++q) {
          unsigned char s = st[il[q]];
          anyK |= (s == 1); allD &= (s != 0);
        }
      } else {
#pragma unroll
        for (int k = 0; k < KNN; ++k) {
          int j = v[k];
          if (j >= base && j < row) {
            unsigned char s = st[j - base];
            anyK |= (s == 1); allD &= (s != 0);
          }
        }
      }
      if (anyK) st[t] = 2; else if (allD) st[t] = 1;
    }
    int nu = __syncthreads_count((int)(st[t] == 0));
    if (nu == 0) break;
  }

  if (valid) out[row] = (st[t] == 1) ? 1 : 0;
}

// kept_knn writer: fully coalesced, one element per thread
__global__ __launch_bounds__(256) void knn_out_kernel(
    const int* __restrict__ knn,
    int* __restrict__ out)
{
  long long e = (long long)blockIdx.x * 256 + threadIdx.x;
  if (e >= (long long)M_ROWS * KNN) return;
  int row = (int)(e >> 6);
  bool keep = out[row] != 0;             // flags are final before this launch
  int idx = knn[e];
  out[M_ROWS + e] = keep ? idx : M_ROWS;
}

extern "C" void kernel_launch(void* const* d_in, const int* in_sizes, int n_in,
                              void* d_out, int out_size, void* d_ws, size_t ws_size,
                              hipStream_t stream) {
  const int* knn = (const int*)d_in[1];
  int* out = (int*)d_out;

  for (int c = 0; c < NCH; ++c)
    flag_chunk_kernel<<<1, CH, 0, stream>>>(knn, out, c * CH);

  const long long ne = (long long)M_ROWS * KNN;
  knn_out_kernel<<<(int)((ne + 255) / 256), 256, 0, stream>>>(knn, out);
}